// Round 11
// baseline (284.085 us; speedup 1.0000x reference)
//
#include <hip/hip_runtime.h>
#include <hip/hip_bf16.h>

#define BB 4
#define SS 1024
#define NSD (BB*SS*64)

typedef __attribute__((ext_vector_type(4))) float f32x4;
typedef __attribute__((ext_vector_type(8))) short bf16x8;

__device__ __forceinline__ float fast_exp2(float x) { return __builtin_amdgcn_exp2f(x); }
__device__ __forceinline__ float fast_rcp(float x)  { return __builtin_amdgcn_rcpf(x); }

__device__ __forceinline__ unsigned short f2bf(float f) {
    unsigned int u = __builtin_bit_cast(unsigned int, f);
    u += 0x7fffu + ((u >> 16) & 1u);
    return (unsigned short)(u >> 16);
}
__device__ __forceinline__ float bf2f(unsigned short u) {
    unsigned int v = (unsigned int)u << 16;
    return __builtin_bit_cast(float, v);
}

// sum of 4 sigmoids 1/(1+eq_d*ek_d) with one reciprocal
__device__ __forceinline__ float sig4(const f32x4 eq, const f32x4 ek) {
    float A = __builtin_fmaf(eq[0], ek[0], 1.0f);
    float B = __builtin_fmaf(eq[1], ek[1], 1.0f);
    float C = __builtin_fmaf(eq[2], ek[2], 1.0f);
    float D = __builtin_fmaf(eq[3], ek[3], 1.0f);
    float AB = A*B, CD = C*D;
    float num = __builtin_fmaf(A+B, CD, (C+D)*AB);
    return num * fast_rcp(AB*CD);
}

// ---------------------------------------------------------------------------
// K1: projections + hi/lo bf16 splits (R5 version, verified at 50.6us total).
// ---------------------------------------------------------------------------
__global__ __launch_bounds__(256) void k_proj(
    const float* __restrict__ x, const float* __restrict__ Wq,
    const float* __restrict__ Wk, const float* __restrict__ bkv,
    const float* __restrict__ Wv,
    unsigned short* __restrict__ qh, unsigned short* __restrict__ ql,
    unsigned short* __restrict__ kh, unsigned short* __restrict__ kl,
    unsigned short* __restrict__ xh, unsigned short* __restrict__ xlo,
    float* __restrict__ exf,
    unsigned short* __restrict__ xT, unsigned short* __restrict__ vT)
{
    __shared__ float xsh[4*68];
    const int t = threadIdx.x;
    const int r = t & 3, cc = t >> 2;
    const int row0 = blockIdx.x * 4;
    if (t < 64) {
        const int rr = t >> 4, seg = (t & 15) * 4;
        *(f32x4*)(xsh + rr*68 + seg) =
            *(const f32x4*)(x + (size_t)(row0 + rr)*64 + seg);
    }
    __syncthreads();

    const float* wqp = Wq + cc*64;
    const float* wkp = Wk + cc*64;
    const float* wvp = Wv + cc*64;
    float aq = 0.f, ak = 0.f, av = 0.f;
    #pragma unroll 4
    for (int e0 = 0; e0 < 64; e0 += 4) {
        f32x4 xv = *(const f32x4*)(xsh + r*68 + e0);
        f32x4 q4 = *(const f32x4*)(wqp + e0);
        f32x4 k4 = *(const f32x4*)(wkp + e0);
        f32x4 v4 = *(const f32x4*)(wvp + e0);
        #pragma unroll
        for (int u = 0; u < 4; ++u) {
            aq = __builtin_fmaf(xv[u], q4[u], aq);
            ak = __builtin_fmaf(xv[u], k4[u], ak);
            av = __builtin_fmaf(xv[u], v4[u], av);
        }
    }
    const int row = row0 + r;
    const int b = row >> 10, srow = row & 1023;
    const float C2 = 2.8853900817779268f;   // 2*log2(e)
    ak += bkv[cc];
    const size_t idx = (size_t)row*64 + cc;
    unsigned short h;
    h = f2bf(aq); qh[idx] = h; ql[idx] = f2bf(aq - bf2f(h));
    h = f2bf(ak); kh[idx] = h; kl[idx] = f2bf(ak - bf2f(h));
    const float xv_ = xsh[r*68 + cc];
    h = f2bf(xv_); xh[idx] = h; xlo[idx] = f2bf(xv_ - bf2f(h));
    exf[idx] = fast_exp2(C2 * xv_);
    xT[((size_t)b*64 + cc)*1024 + srow] = h;
    vT[((size_t)b*64 + cc)*1024 + srow] = f2bf(av);
}

// ---------------------------------------------------------------------------
// K2: fused scores+softmax+PV (R5 version verbatim — best total 50.6us).
// ---------------------------------------------------------------------------
__global__ __launch_bounds__(256) void k_fused(
    const unsigned short* __restrict__ xh, const unsigned short* __restrict__ xlo,
    const unsigned short* __restrict__ qh, const unsigned short* __restrict__ ql,
    const unsigned short* __restrict__ kh, const unsigned short* __restrict__ kl,
    const float* __restrict__ exf,
    const unsigned short* __restrict__ xT, const unsigned short* __restrict__ vT,
    const float* __restrict__ attn_scale,
    float* __restrict__ po, float* __restrict__ lb)
{
    __shared__ float sexq[32*68];
    __shared__ float sexk[64*68];
    __shared__ unsigned short Pl[32*72];
    __shared__ float lpart[4][16];
    __shared__ float l_arr[32];

    const int t = threadIdx.x;
    const int bx = blockIdx.x;
    const int lane = t & 63, wv = t >> 6;
    const int l15 = lane & 15, g = lane >> 4;
    const float LOG2E = 1.4426950408889634f;

    if (bx < 512) {
        // ================= branch 3 =================
        const int s4 = bx & 3, b = (bx >> 2) & 3;
        const int qt3 = 31 - (bx >> 4);
        const int q0 = qt3 * 32;
        const int nc = (qt3 >> 1) + 1;

        {   // stage sexq [32][68]
            const int rw = t >> 3, seg = (t & 7) * 8;
            const float* gsrc = exf + ((size_t)b*SS + q0 + rw)*64 + seg;
            f32x4* dst = (f32x4*)(sexq + rw*68 + seg);
            dst[0] = ((const f32x4*)gsrc)[0];
            dst[1] = ((const f32x4*)gsrc)[1];
        }
        __syncthreads();

        const int qp = t >> 4, kb = t & 15;     // rows qp*2+{0,1}, cols kb+16j
        const int qh_w = wv & 1, dbase = (wv >> 1) * 32;
        float lacc0 = 0.f, lacc1 = 0.f;
        f32x4 oacc0 = {0,0,0,0}, oacc1 = {0,0,0,0};

        for (int c = s4; c < nc; c += 4) {
            const int kc = c * 64;
            {   // stage sexk [64][68]
                const int rw = t >> 2, seg = (t & 3) * 16;
                const float* gsrc = exf + ((size_t)b*SS + kc + rw)*64 + seg;
                f32x4* dst = (f32x4*)(sexk + rw*68 + seg);
                #pragma unroll
                for (int i = 0; i < 4; ++i) dst[i] = ((const f32x4*)gsrc)[i];
            }
            __syncthreads();

            float ar0[4] = {0.f,0.f,0.f,0.f};
            float ar1[4] = {0.f,0.f,0.f,0.f};
            #pragma unroll 4
            for (int d0 = 0; d0 < 64; d0 += 4) {
                f32x4 eq0 = *(const f32x4*)(sexq + (qp*2+0)*68 + d0);
                f32x4 eq1 = *(const f32x4*)(sexq + (qp*2+1)*68 + d0);
                #pragma unroll
                for (int j = 0; j < 4; ++j) {
                    f32x4 ek = *(const f32x4*)(sexk + (kb + 16*j)*68 + d0);
                    ar0[j] += sig4(eq0, ek);
                    ar1[j] += sig4(eq1, ek);
                }
            }
            // p = e^{s3-32} = exp2(fma(ar, -2*log2e, 32*log2e)), masked
            #pragma unroll
            for (int j = 0; j < 4; ++j) {
                const int kg = kc + kb + 16*j;
                float e0 = (kg <= q0 + qp*2 + 0)
                    ? fast_exp2(__builtin_fmaf(ar0[j], -2.8853900817779268f, 46.166241308446475f)) : 0.f;
                float e1 = (kg <= q0 + qp*2 + 1)
                    ? fast_exp2(__builtin_fmaf(ar1[j], -2.8853900817779268f, 46.166241308446475f)) : 0.f;
                lacc0 += e0; lacc1 += e1;
                Pl[(qp*2+0)*72 + kb + 16*j] = f2bf(e0);
                Pl[(qp*2+1)*72 + kb + 16*j] = f2bf(e1);
            }
            __syncthreads();
            // PV: wave -> (qh_w, dbase); V B-frags direct from global xT
            const unsigned short* vb = xT + (size_t)b*64*1024;
            #pragma unroll
            for (int ks = 0; ks < 2; ++ks) {
                bf16x8 af = *(const bf16x8*)(Pl + (qh_w*16 + l15)*72 + ks*32 + g*8);
                bf16x8 b0 = *(const bf16x8*)(vb + (size_t)(dbase + l15)*1024 + kc + ks*32 + g*8);
                bf16x8 b1 = *(const bf16x8*)(vb + (size_t)(dbase + 16 + l15)*1024 + kc + ks*32 + g*8);
                oacc0 = __builtin_amdgcn_mfma_f32_16x16x32_bf16(af, b0, oacc0, 0, 0, 0);
                oacc1 = __builtin_amdgcn_mfma_f32_16x16x32_bf16(af, b1, oacc1, 0, 0, 0);
            }
            __syncthreads();
        }
        // row sums: reduce over kb within each 16-lane group
        #pragma unroll
        for (int off = 8; off >= 1; off >>= 1) {
            lacc0 += __shfl_xor(lacc0, off, 64);
            lacc1 += __shfl_xor(lacc1, off, 64);
        }
        if (kb == 0) { l_arr[qp*2] = lacc0; l_arr[qp*2+1] = lacc1; }
        __syncthreads();
        const size_t slot = 4 + s4;
        if (t < 32) lb[slot*((size_t)BB*SS) + (size_t)b*SS + q0 + t] = l_arr[t];
        float* pob = po + slot*((size_t)NSD) + ((size_t)b*SS + q0)*64;
        #pragma unroll
        for (int i = 0; i < 4; ++i) {
            const int rr = qh_w*16 + g*4 + i;
            pob[(size_t)rr*64 + dbase + l15]      = oacc0[i];
            pob[(size_t)rr*64 + dbase + 16 + l15] = oacc1[i];
        }
    } else {
        // ================= branches 1,2 =================
        const int y = bx - 512;
        const int split = y & 1, b = (y >> 1) & 3;
        const int qt = 63 - ((y >> 3) & 63);
        const int br = (y >> 9) & 1;
        const int q0 = qt * 16;
        const int nc = (qt >> 2) + 1;

        const unsigned short* Ah_p = (br ? qh : xh) + ((size_t)b*SS + q0)*64;
        const unsigned short* Al_p = (br ? ql : xlo) + ((size_t)b*SS + q0)*64;
        const unsigned short* Bh_p = (br ? kh : xh) + (size_t)b*SS*64;
        const unsigned short* Bl_p = (br ? kl : xlo) + (size_t)b*SS*64;
        const unsigned short* Vb   = (br ? vT : xT) + (size_t)b*64*1024;

        const int ko = g * 8;
        bf16x8 Ah0 = *(const bf16x8*)(Ah_p + (size_t)l15*64 + ko);
        bf16x8 Ah1 = *(const bf16x8*)(Ah_p + (size_t)l15*64 + 32 + ko);
        bf16x8 Al0 = *(const bf16x8*)(Al_p + (size_t)l15*64 + ko);
        bf16x8 Al1 = *(const bf16x8*)(Al_p + (size_t)l15*64 + 32 + ko);

        const float pscale = br ? (0.125f * attn_scale[0] * LOG2E) : LOG2E;
        const float pshift = br ? 0.f : (-64.f * LOG2E);

        f32x4 lacc = {0,0,0,0};
        f32x4 oacc = {0,0,0,0};

        for (int c = split; c < nc; c += 2) {
            const int kc = c * 64;
            const int krow = kc + wv*16 + l15;
            bf16x8 Bh0 = *(const bf16x8*)(Bh_p + (size_t)krow*64 + ko);
            bf16x8 Bh1 = *(const bf16x8*)(Bh_p + (size_t)krow*64 + 32 + ko);
            bf16x8 Bl0 = *(const bf16x8*)(Bl_p + (size_t)krow*64 + ko);
            bf16x8 Bl1 = *(const bf16x8*)(Bl_p + (size_t)krow*64 + 32 + ko);
            f32x4 s = {0,0,0,0};
            s = __builtin_amdgcn_mfma_f32_16x16x32_bf16(Ah0, Bh0, s, 0, 0, 0);
            s = __builtin_amdgcn_mfma_f32_16x16x32_bf16(Ah1, Bh1, s, 0, 0, 0);
            s = __builtin_amdgcn_mfma_f32_16x16x32_bf16(Ah0, Bl0, s, 0, 0, 0);
            s = __builtin_amdgcn_mfma_f32_16x16x32_bf16(Ah1, Bl1, s, 0, 0, 0);
            s = __builtin_amdgcn_mfma_f32_16x16x32_bf16(Al0, Bh0, s, 0, 0, 0);
            s = __builtin_amdgcn_mfma_f32_16x16x32_bf16(Al1, Bh1, s, 0, 0, 0);
            const int kg = kc + wv*16 + l15;
            #pragma unroll
            for (int i = 0; i < 4; ++i) {
                const int q = q0 + g*4 + i;
                float e = (kg <= q) ? fast_exp2(__builtin_fmaf(s[i], pscale, pshift)) : 0.f;
                lacc[i] += e;
                Pl[(g*4+i)*72 + wv*16 + l15] = f2bf(e);
            }
            __syncthreads();
            #pragma unroll
            for (int ks = 0; ks < 2; ++ks) {
                bf16x8 af = *(const bf16x8*)(Pl + l15*72 + ks*32 + g*8);
                bf16x8 bf_ = *(const bf16x8*)(Vb + (size_t)(wv*16 + l15)*1024 + kc + ks*32 + g*8);
                oacc = __builtin_amdgcn_mfma_f32_16x16x32_bf16(af, bf_, oacc, 0, 0, 0);
            }
            __syncthreads();
        }
        #pragma unroll
        for (int off = 8; off >= 1; off >>= 1) {
            lacc[0] += __shfl_xor(lacc[0], off, 64);
            lacc[1] += __shfl_xor(lacc[1], off, 64);
            lacc[2] += __shfl_xor(lacc[2], off, 64);
            lacc[3] += __shfl_xor(lacc[3], off, 64);
        }
        if (l15 == 0) {
            #pragma unroll
            for (int i = 0; i < 4; ++i) lpart[wv][g*4 + i] = lacc[i];
        }
        __syncthreads();
        const size_t slot = (size_t)(br*2 + split);
        if (t < 16) {
            float l = lpart[0][t] + lpart[1][t] + lpart[2][t] + lpart[3][t];
            lb[slot*((size_t)BB*SS) + (size_t)b*SS + q0 + t] = l;
        }
        float* pob = po + slot*((size_t)NSD) + ((size_t)b*SS + q0)*64;
        #pragma unroll
        for (int i = 0; i < 4; ++i)
            pob[(size_t)(g*4 + i)*64 + wv*16 + l15] = oacc[i];
    }
}

// ---------------------------------------------------------------------------
// K3: merge (R5 version verbatim).
// ---------------------------------------------------------------------------
__global__ __launch_bounds__(256) void k_comb(
    const float* __restrict__ po, const float* __restrict__ lb,
    const float* __restrict__ attn_w, float* __restrict__ out)
{
    const int v = blockIdx.x*256 + threadIdx.x;      // f32x4 index over [B,S,D]
    const int qg = v >> 4;                           // global row b*S+q
    const float aw0 = attn_w[0], aw1 = attn_w[1], aw2 = attn_w[2];
    const float iws = fast_rcp(aw0 + aw1 + aw2);
    const f32x4* p = (const f32x4*)po;
    const int NQ = BB*SS;

    f32x4 s01 = p[(size_t)0*65536 + v] + p[(size_t)1*65536 + v];
    f32x4 s23 = p[(size_t)2*65536 + v] + p[(size_t)3*65536 + v];
    f32x4 s47 = (p[(size_t)4*65536 + v] + p[(size_t)5*65536 + v])
              + (p[(size_t)6*65536 + v] + p[(size_t)7*65536 + v]);
    const float f0 = aw0 * iws * fast_rcp(lb[0*NQ + qg] + lb[1*NQ + qg]);
    const float f1 = aw1 * iws * fast_rcp(lb[2*NQ + qg] + lb[3*NQ + qg]);
    const float f2 = aw2 * iws * fast_rcp(lb[4*NQ + qg] + lb[5*NQ + qg]
                                        + lb[6*NQ + qg] + lb[7*NQ + qg]);
    f32x4 o;
    #pragma unroll
    for (int u = 0; u < 4; ++u)
        o[u] = __builtin_fmaf(s01[u], f0,
               __builtin_fmaf(s23[u], f1, s47[u]*f2));
    ((f32x4*)out)[v] = o;
}

// ---------------------------------------------------------------------------
// PROBE 1: pure-register sig4 throughput. 8x real br3 inner volume.
// asm "+v" per iter prevents loop-invariant CSE (rule #17).
// Model: ~43us. >=90us => instruction inflation in sig4 lowering.
// ---------------------------------------------------------------------------
__global__ __launch_bounds__(256) void p_reg(
    const float* __restrict__ exf, float* __restrict__ sink)
{
    const int t = threadIdx.x, bx = blockIdx.x;
    const int qt3 = 31 - ((bx >> 4) & 31);
    const int nc = (qt3 >> 1) + 1;
    const int off = (((bx << 8) + t) % 10000) * 24;
    const float* base = exf + off;
    f32x4 eq0 = *(const f32x4*)(base +  0);
    f32x4 eq1 = *(const f32x4*)(base +  4);
    f32x4 ek0 = *(const f32x4*)(base +  8);
    f32x4 ek1 = *(const f32x4*)(base + 12);
    f32x4 ek2 = *(const f32x4*)(base + 16);
    f32x4 ek3 = *(const f32x4*)(base + 20);
    float ar0[4] = {0,0,0,0}, ar1[4] = {0,0,0,0};
    for (int rep = 0; rep < 2; ++rep) {
        for (int c = 0; c < nc; ++c) {
            for (int m = 0; m < 16; ++m) {
                asm volatile("" : "+v"(eq0), "+v"(eq1), "+v"(ek0),
                                  "+v"(ek1), "+v"(ek2), "+v"(ek3));
                ar0[0] += sig4(eq0, ek0); ar0[1] += sig4(eq0, ek1);
                ar0[2] += sig4(eq0, ek2); ar0[3] += sig4(eq0, ek3);
                ar1[0] += sig4(eq1, ek0); ar1[1] += sig4(eq1, ek1);
                ar1[2] += sig4(eq1, ek2); ar1[3] += sig4(eq1, ek3);
            }
        }
    }
    float s = (ar0[0]+ar0[1]+ar0[2]+ar0[3]) + (ar1[0]+ar1[1]+ar1[2]+ar1[3]);
    sink[(size_t)bx*256 + t] = s;
}

// ---------------------------------------------------------------------------
// PROBE 2: sig4 + r5's exact LDS access pattern (6x ds_read_b128 per iter,
// 68-stride). Staged once; memory clobber per chunk blocks cross-chunk CSE.
// Model: ~65-75us (CU-shared DS pipe). >=150us => LDS pathology.
// ---------------------------------------------------------------------------
__global__ __launch_bounds__(256) void p_lds(
    const float* __restrict__ exf, float* __restrict__ sink)
{
    __shared__ float sexq[32*68];
    __shared__ float sexk[64*68];
    const int t = threadIdx.x, bx = blockIdx.x;
    const int qt3 = 31 - ((bx >> 4) & 31);
    const int nc = (qt3 >> 1) + 1;
    const int b = bx & 3;

    {   // stage q-side (32 rows x 64)
        const int rw = t >> 3, seg = (t & 7) * 8;
        const float* g = exf + ((size_t)b*SS + rw)*64 + seg;
        f32x4* dst = (f32x4*)(sexq + rw*68 + seg);
        dst[0] = ((const f32x4*)g)[0];
        dst[1] = ((const f32x4*)g)[1];
    }
    {   // stage k-side (64 rows x 64)
        const int rw = t >> 2, seg = (t & 3) * 16;
        const float* g = exf + ((size_t)b*SS + 64 + rw)*64 + seg;
        f32x4* dst = (f32x4*)(sexk + rw*68 + seg);
        #pragma unroll
        for (int i = 0; i < 4; ++i) dst[i] = ((const f32x4*)g)[i];
    }
    __syncthreads();

    const int qp = t >> 4, kb = t & 15;
    float ar0[4] = {0,0,0,0}, ar1[4] = {0,0,0,0};
    for (int rep = 0; rep < 2; ++rep) {
        for (int c = 0; c < nc; ++c) {
            asm volatile("" ::: "memory");   // force re-read each chunk
            #pragma unroll 4
            for (int d0 = 0; d0 < 64; d0 += 4) {
                f32x4 eq0 = *(const f32x4*)(sexq + (qp*2+0)*68 + d0);
                f32x4 eq1 = *(const f32x4*)(sexq + (qp*2+1)*68 + d0);
                #pragma unroll
                for (int j = 0; j < 4; ++j) {
                    f32x4 ek = *(const f32x4*)(sexk + (kb + 16*j)*68 + d0);
                    ar0[j] += sig4(eq0, ek);
                    ar1[j] += sig4(eq1, ek);
                }
            }
        }
    }
    float s = (ar0[0]+ar0[1]+ar0[2]+ar0[3]) + (ar1[0]+ar1[1]+ar1[2]+ar1[3]);
    sink[(size_t)131072 + (size_t)bx*256 + t] = s;
}

extern "C" void kernel_launch(void* const* d_in, const int* in_sizes, int n_in,
                              void* d_out, int out_size, void* d_ws, size_t ws_size,
                              hipStream_t stream) {
    (void)in_sizes; (void)n_in; (void)out_size; (void)ws_size;
    const float* x          = (const float*)d_in[0];
    const float* Wq         = (const float*)d_in[1];
    const float* Wk         = (const float*)d_in[2];
    const float* bk         = (const float*)d_in[3];
    const float* Wv         = (const float*)d_in[4];
    const float* attn_w     = (const float*)d_in[5];
    const float* attn_scale = (const float*)d_in[6];
    float* out              = (float*)d_out;

    // workspace carve-up (~15 MB)
    float* exf = (float*)d_ws;                            // [B,S,64] f32
    unsigned short* qh  = (unsigned short*)(exf + NSD);   // 6 bf16 [B,S,64]
    unsigned short* ql  = qh  + NSD;
    unsigned short* kh  = ql  + NSD;
    unsigned short* kl  = kh  + NSD;
    unsigned short* xh  = kl  + NSD;
    unsigned short* xlo = xh  + NSD;
    unsigned short* xT  = xlo + NSD;                      // bf16 [B,64,S]
    unsigned short* vT  = xT  + NSD;
    float* po = (float*)(vT + NSD);                       // [8][B,S,64] f32
    float* lb = po + (size_t)8*NSD;                       // [8][B*S]
    float* sink = lb + (size_t)8*BB*SS;                   // probe scratch

    k_proj <<<1024, 256, 0, stream>>>(x, Wq, Wk, bk, Wv,
                                      qh, ql, kh, kl, xh, xlo, exf, xT, vT);
    k_fused<<<1536, 256, 0, stream>>>(xh, xlo, qh, ql, kh, kl, exf, xT, vT,
                                      attn_scale, po, lb);
    k_comb <<<256, 256, 0, stream>>>(po, lb, attn_w, out);
    // measurement probes (dead outputs; deliberately sized > fill-kernel 40us)
    p_reg  <<<512, 256, 0, stream>>>(exf, sink);
    p_lds  <<<512, 256, 0, stream>>>(exf, sink);
}

// Round 12
// 52.066 us; speedup vs baseline: 5.4562x; 5.4562x over previous
//
#include <hip/hip_runtime.h>
#include <hip/hip_bf16.h>

#define BB 4
#define SS 1024
#define NSD (BB*SS*64)

typedef __attribute__((ext_vector_type(4))) float f32x4;
typedef __attribute__((ext_vector_type(8))) short bf16x8;

__device__ __forceinline__ float fast_exp2(float x) { return __builtin_amdgcn_exp2f(x); }
__device__ __forceinline__ float fast_rcp(float x)  { return __builtin_amdgcn_rcpf(x); }

__device__ __forceinline__ unsigned short f2bf(float f) {
    unsigned int u = __builtin_bit_cast(unsigned int, f);
    u += 0x7fffu + ((u >> 16) & 1u);
    return (unsigned short)(u >> 16);
}
__device__ __forceinline__ float bf2f(unsigned short u) {
    unsigned int v = (unsigned int)u << 16;
    return __builtin_bit_cast(float, v);
}

// sum of 4 sigmoids 1/(1+eq_d*ek_d) with one reciprocal
__device__ __forceinline__ float sig4(const f32x4 eq, const f32x4 ek) {
    float A = __builtin_fmaf(eq[0], ek[0], 1.0f);
    float B = __builtin_fmaf(eq[1], ek[1], 1.0f);
    float C = __builtin_fmaf(eq[2], ek[2], 1.0f);
    float D = __builtin_fmaf(eq[3], ek[3], 1.0f);
    float AB = A*B, CD = C*D;
    float num = __builtin_fmaf(A+B, CD, (C+D)*AB);
    return num * fast_rcp(AB*CD);
}

// ---------------------------------------------------------------------------
// K1: projections + hi/lo bf16 splits (verified r4-r11).
// ---------------------------------------------------------------------------
__global__ __launch_bounds__(256) void k_proj(
    const float* __restrict__ x, const float* __restrict__ Wq,
    const float* __restrict__ Wk, const float* __restrict__ bkv,
    const float* __restrict__ Wv,
    unsigned short* __restrict__ qh, unsigned short* __restrict__ ql,
    unsigned short* __restrict__ kh, unsigned short* __restrict__ kl,
    unsigned short* __restrict__ xh, unsigned short* __restrict__ xlo,
    float* __restrict__ exf,
    unsigned short* __restrict__ xT, unsigned short* __restrict__ vT)
{
    __shared__ float xsh[4*68];
    const int t = threadIdx.x;
    const int r = t & 3, cc = t >> 2;
    const int row0 = blockIdx.x * 4;
    if (t < 64) {
        const int rr = t >> 4, seg = (t & 15) * 4;
        *(f32x4*)(xsh + rr*68 + seg) =
            *(const f32x4*)(x + (size_t)(row0 + rr)*64 + seg);
    }
    __syncthreads();

    const float* wqp = Wq + cc*64;
    const float* wkp = Wk + cc*64;
    const float* wvp = Wv + cc*64;
    float aq = 0.f, ak = 0.f, av = 0.f;
    #pragma unroll 4
    for (int e0 = 0; e0 < 64; e0 += 4) {
        f32x4 xv = *(const f32x4*)(xsh + r*68 + e0);
        f32x4 q4 = *(const f32x4*)(wqp + e0);
        f32x4 k4 = *(const f32x4*)(wkp + e0);
        f32x4 v4 = *(const f32x4*)(wvp + e0);
        #pragma unroll
        for (int u = 0; u < 4; ++u) {
            aq = __builtin_fmaf(xv[u], q4[u], aq);
            ak = __builtin_fmaf(xv[u], k4[u], ak);
            av = __builtin_fmaf(xv[u], v4[u], av);
        }
    }
    const int row = row0 + r;
    const int b = row >> 10, srow = row & 1023;
    const float C2 = 2.8853900817779268f;   // 2*log2(e)
    ak += bkv[cc];
    const size_t idx = (size_t)row*64 + cc;
    unsigned short h;
    h = f2bf(aq); qh[idx] = h; ql[idx] = f2bf(aq - bf2f(h));
    h = f2bf(ak); kh[idx] = h; kl[idx] = f2bf(ak - bf2f(h));
    const float xv_ = xsh[r*68 + cc];
    h = f2bf(xv_); xh[idx] = h; xlo[idx] = f2bf(xv_ - bf2f(h));
    exf[idx] = fast_exp2(C2 * xv_);
    xT[((size_t)b*64 + cc)*1024 + srow] = h;
    vT[((size_t)b*64 + cc)*1024 + srow] = f2bf(av);
}

// ---------------------------------------------------------------------------
// K2: merged fused kernel, 1600 blocks x 256.
//  bx < 576 : branch 3 v6. Block=(b, qt32 desc, cg); wave wv -> chunk
//    c=cg*4+wv (32k), one UNIFORM job/wave (no tail). Shared swizzled eq
//    (8KB, 1 barrier); per-wave swizzled ek (8KB, no barriers); lane tile
//    4q x 4k (DS:VALU = 0.75, probe-calibrated); P per-wave [32][40] ->
//    MFMA vs xT; end-of-block cross-wave O-reduce via dead ek buffers.
//    Slot 4+cg (k_comb masks s >= ns(row)).
//  bx >= 576 : branches 1,2 (split-bf16 MFMA scores; verified r6-r11),
//    smem aliased. Slots 0..3.
// LDS 50.5KB -> 3 blocks/CU; 576 br3 blocks fully resident; br12 backfills
// (MFMA-pipe waves co-schedule with br3's VALU waves, m114 overlap).
// ---------------------------------------------------------------------------
__global__ __launch_bounds__(256) void k_fused(
    const unsigned short* __restrict__ xh, const unsigned short* __restrict__ xlo,
    const unsigned short* __restrict__ qh, const unsigned short* __restrict__ ql,
    const unsigned short* __restrict__ kh, const unsigned short* __restrict__ kl,
    const float* __restrict__ exf,
    const unsigned short* __restrict__ xT, const unsigned short* __restrict__ vT,
    const float* __restrict__ attn_scale,
    float* __restrict__ po, float* __restrict__ lb)
{
    // carve: eq[2048] | ek 4x2048 | P 4x640 (as u16 4x[32][40]) | lpart 128
    __shared__ float smem[12928];
    const int t = threadIdx.x;
    const int bx = blockIdx.x;
    const int lane = t & 63, wv = t >> 6;
    const int l15 = lane & 15, g = lane >> 4;
    const float LOG2E = 1.4426950408889634f;

    if (bx < 576) {
        // ================= branch 3 =================
        const int b = bx / 144;
        int rr = bx % 144;
        int qt32 = 31;
        while (rr >= ((qt32 >> 2) + 1)) { rr -= (qt32 >> 2) + 1; --qt32; }
        const int cg = rr;
        const int q0 = qt32 * 32;
        const int c = cg*4 + wv;
        const bool active = (c <= qt32);
        const int kc = c * 32;
        const int l7 = lane & 7, lk3 = lane >> 3;

        float* eqs = smem;                       // [32][64] swizzled, shared
        float* ekw = smem + 2048 + wv*2048;      // [32][64] swizzled, per-wave
        unsigned short* Plw = (unsigned short*)(smem + 2048 + 8192) + wv*1280;
        float* lpart = smem + 2048 + 8192 + 2560;  // [4][32]

        {   // stage eq cooperatively (512 f32x4 by 256 threads)
            const float* src = exf + ((size_t)b*SS + q0)*64;
            #pragma unroll
            for (int ii = 0; ii < 2; ++ii) {
                const int idx = t + 256*ii;
                const int r0 = idx >> 4, mq = idx & 15;
                *(f32x4*)(eqs + r0*64 + ((mq ^ (r0 & 7)) << 2)) =
                    *(const f32x4*)(src + r0*64 + mq*4);
            }
        }
        if (active) {   // stage own ek (8 f32x4/lane, coalesced, swizzled)
            const float* srck = exf + ((size_t)b*SS + kc)*64;
            #pragma unroll
            for (int ii = 0; ii < 8; ++ii) {
                const int idx = lane + 64*ii;
                const int r0 = idx >> 4, mq = idx & 15;
                *(f32x4*)(ekw + r0*64 + ((mq ^ (r0 & 7)) << 2)) =
                    *(const f32x4*)(srck + r0*64 + mq*4);
            }
        }
        __syncthreads();

        f32x4 acc[2][4];
        #pragma unroll
        for (int a_ = 0; a_ < 2; ++a_)
            #pragma unroll
            for (int d_ = 0; d_ < 4; ++d_)
                acc[a_][d_] = (f32x4){0.f,0.f,0.f,0.f};
        float lrow[4] = {0.f,0.f,0.f,0.f};

        if (active) {
            float ar[4][4] = {};
            #pragma unroll 4
            for (int m = 0; m < 16; ++m) {
                const int oq = (m ^ l7) << 2;
                const int ok = (m ^ lk3) << 2;
                f32x4 eqv[4], ekv[4];
                #pragma unroll
                for (int i = 0; i < 4; ++i)
                    eqv[i] = *(const f32x4*)(eqs + (l7 + 8*i)*64 + oq);
                #pragma unroll
                for (int j = 0; j < 4; ++j)
                    ekv[j] = *(const f32x4*)(ekw + (lk3 + 8*j)*64 + ok);
                #pragma unroll
                for (int i = 0; i < 4; ++i)
                    #pragma unroll
                    for (int j = 0; j < 4; ++j)
                        ar[i][j] += sig4(eqv[i], ekv[j]);
            }
            // p = e^{s3-32}, s3 = 64-2ar; causal mask; P->LDS; row sums
            #pragma unroll
            for (int i = 0; i < 4; ++i) {
                const int q = q0 + l7 + 8*i;
                #pragma unroll
                for (int j = 0; j < 4; ++j) {
                    const int k = kc + lk3 + 8*j;
                    float e = (k <= q)
                        ? fast_exp2(__builtin_fmaf(ar[i][j], -2.8853900817779268f,
                                                   46.166241308446475f))
                        : 0.f;
                    lrow[i] += e;
                    Plw[(l7 + 8*i)*40 + lk3 + 8*j] = f2bf(e);
                }
            }
            // PV: 2 q-halves x 4 d-blocks, B-frags direct from xT
            const unsigned short* vb = xT + (size_t)b*64*1024;
            #pragma unroll
            for (int qh2 = 0; qh2 < 2; ++qh2) {
                bf16x8 af = *(const bf16x8*)(Plw + (qh2*16 + l15)*40 + g*8);
                #pragma unroll
                for (int db = 0; db < 4; ++db) {
                    bf16x8 bf_ = *(const bf16x8*)(vb + (size_t)(db*16 + l15)*1024 + kc + g*8);
                    acc[qh2][db] = __builtin_amdgcn_mfma_f32_16x16x32_bf16(af, bf_, acc[qh2][db], 0, 0, 0);
                }
            }
        }
        // row-sum reduce across lanes sharing q-row (stride-8 ladder)
        #pragma unroll
        for (int i = 0; i < 4; ++i) {
            lrow[i] += __shfl_xor(lrow[i], 8, 64);
            lrow[i] += __shfl_xor(lrow[i], 16, 64);
            lrow[i] += __shfl_xor(lrow[i], 32, 64);
        }
        if (lane < 8) {
            #pragma unroll
            for (int i = 0; i < 4; ++i) lpart[wv*32 + l7 + 8*i] = lrow[i];
        }
        // O partial -> dead ek buffer, flat-swizzled (r8 pattern)
        #pragma unroll
        for (int qh2 = 0; qh2 < 2; ++qh2)
            #pragma unroll
            for (int db = 0; db < 4; ++db)
                #pragma unroll
                for (int i = 0; i < 4; ++i) {
                    const int row = qh2*16 + g*4 + i;
                    const int col = db*16 + l15;
                    const int L = (row << 4) + (col >> 2);
                    const int P = L ^ ((L >> 3) & 7);
                    ekw[(P << 2) + (col & 3)] = acc[qh2][db][i];
                }
        __syncthreads();
        // cross-wave reduce, write po/lb slot 4+cg
        {
            const int L0 = t*2,     P0 = L0 ^ ((L0 >> 3) & 7);
            const int L1 = t*2 + 1, P1 = L1 ^ ((L1 >> 3) & 7);
            f32x4 s0 = {0,0,0,0}, s1 = {0,0,0,0};
            #pragma unroll
            for (int w = 0; w < 4; ++w) {
                const float* ob = smem + 2048 + w*2048;
                s0 += *(const f32x4*)(ob + (P0 << 2));
                s1 += *(const f32x4*)(ob + (P1 << 2));
            }
            float* pob = po + (size_t)(4+cg)*NSD + ((size_t)b*SS + q0)*64;
            *(f32x4*)(pob + (size_t)(L0 >> 4)*64 + (L0 & 15)*4) = s0;
            *(f32x4*)(pob + (size_t)(L1 >> 4)*64 + (L1 & 15)*4) = s1;
            if (t < 32) {
                float l = lpart[t] + lpart[32 + t] + lpart[64 + t] + lpart[96 + t];
                lb[(size_t)(4+cg)*(BB*SS) + (size_t)b*SS + q0 + t] = l;
            }
        }
    } else {
        // ================= branches 1,2 (verified path, smem aliased) =======
        unsigned short* Pl = (unsigned short*)smem;       // [16][72] u16
        float* lpart = smem + 1024;                       // [4][16]
        const int y = bx - 576;
        const int split = y & 1, b = (y >> 1) & 3;
        const int qt = 63 - ((y >> 3) & 63);
        const int br = (y >> 9) & 1;
        const int q0 = qt * 16;
        const int nc = (qt >> 2) + 1;

        const unsigned short* Ah_p = (br ? qh : xh) + ((size_t)b*SS + q0)*64;
        const unsigned short* Al_p = (br ? ql : xlo) + ((size_t)b*SS + q0)*64;
        const unsigned short* Bh_p = (br ? kh : xh) + (size_t)b*SS*64;
        const unsigned short* Bl_p = (br ? kl : xlo) + (size_t)b*SS*64;
        const unsigned short* Vb   = (br ? vT : xT) + (size_t)b*64*1024;

        const int ko = g * 8;
        bf16x8 Ah0 = *(const bf16x8*)(Ah_p + (size_t)l15*64 + ko);
        bf16x8 Ah1 = *(const bf16x8*)(Ah_p + (size_t)l15*64 + 32 + ko);
        bf16x8 Al0 = *(const bf16x8*)(Al_p + (size_t)l15*64 + ko);
        bf16x8 Al1 = *(const bf16x8*)(Al_p + (size_t)l15*64 + 32 + ko);

        const float pscale = br ? (0.125f * attn_scale[0] * LOG2E) : LOG2E;
        const float pshift = br ? 0.f : (-64.f * LOG2E);

        f32x4 lacc = {0,0,0,0};
        f32x4 oacc = {0,0,0,0};

        for (int cc2 = split; cc2 < nc; cc2 += 2) {
            const int kc = cc2 * 64;
            const int krow = kc + wv*16 + l15;
            bf16x8 Bh0 = *(const bf16x8*)(Bh_p + (size_t)krow*64 + ko);
            bf16x8 Bh1 = *(const bf16x8*)(Bh_p + (size_t)krow*64 + 32 + ko);
            bf16x8 Bl0 = *(const bf16x8*)(Bl_p + (size_t)krow*64 + ko);
            bf16x8 Bl1 = *(const bf16x8*)(Bl_p + (size_t)krow*64 + 32 + ko);
            f32x4 s = {0,0,0,0};
            s = __builtin_amdgcn_mfma_f32_16x16x32_bf16(Ah0, Bh0, s, 0, 0, 0);
            s = __builtin_amdgcn_mfma_f32_16x16x32_bf16(Ah1, Bh1, s, 0, 0, 0);
            s = __builtin_amdgcn_mfma_f32_16x16x32_bf16(Ah0, Bl0, s, 0, 0, 0);
            s = __builtin_amdgcn_mfma_f32_16x16x32_bf16(Ah1, Bl1, s, 0, 0, 0);
            s = __builtin_amdgcn_mfma_f32_16x16x32_bf16(Al0, Bh0, s, 0, 0, 0);
            s = __builtin_amdgcn_mfma_f32_16x16x32_bf16(Al1, Bh1, s, 0, 0, 0);
            const int kg = kc + wv*16 + l15;
            #pragma unroll
            for (int i = 0; i < 4; ++i) {
                const int q = q0 + g*4 + i;
                float e = (kg <= q) ? fast_exp2(__builtin_fmaf(s[i], pscale, pshift)) : 0.f;
                lacc[i] += e;
                Pl[(g*4+i)*72 + wv*16 + l15] = f2bf(e);
            }
            __syncthreads();
            #pragma unroll
            for (int ks = 0; ks < 2; ++ks) {
                bf16x8 af = *(const bf16x8*)(Pl + l15*72 + ks*32 + g*8);
                bf16x8 bf_ = *(const bf16x8*)(Vb + (size_t)(wv*16 + l15)*1024 + kc + ks*32 + g*8);
                oacc = __builtin_amdgcn_mfma_f32_16x16x32_bf16(af, bf_, oacc, 0, 0, 0);
            }
            __syncthreads();
        }
        #pragma unroll
        for (int off = 8; off >= 1; off >>= 1) {
            lacc[0] += __shfl_xor(lacc[0], off, 64);
            lacc[1] += __shfl_xor(lacc[1], off, 64);
            lacc[2] += __shfl_xor(lacc[2], off, 64);
            lacc[3] += __shfl_xor(lacc[3], off, 64);
        }
        if (l15 == 0) {
            #pragma unroll
            for (int i = 0; i < 4; ++i) lpart[wv*16 + g*4 + i] = lacc[i];
        }
        __syncthreads();
        const size_t slot = (size_t)(br*2 + split);
        if (t < 16) {
            float l = lpart[t] + lpart[16 + t] + lpart[32 + t] + lpart[48 + t];
            lb[slot*((size_t)BB*SS) + (size_t)b*SS + q0 + t] = l;
        }
        float* pob = po + slot*((size_t)NSD) + ((size_t)b*SS + q0)*64;
        #pragma unroll
        for (int i = 0; i < 4; ++i)
            pob[(size_t)(g*4 + i)*64 + wv*16 + l15] = oacc[i];
    }
}

// ---------------------------------------------------------------------------
// K3: out = w0*(p0+p1)/(l0+l1) + w1*(p2+p3)/(l2+l3) + w2*(br3 slots s < ns)
// ns per row = (row_in_batch >> 7) + 1  (1..8, 32q x 4x32k chunk groups).
// ---------------------------------------------------------------------------
__global__ __launch_bounds__(256) void k_comb(
    const float* __restrict__ po, const float* __restrict__ lb,
    const float* __restrict__ attn_w, float* __restrict__ out)
{
    const int v = blockIdx.x*256 + threadIdx.x;      // f32x4 index over [B,S,D]
    const int qg = v >> 4;                           // global row b*S+q
    const int ns = ((qg & 1023) >> 7) + 1;
    const float aw0 = attn_w[0], aw1 = attn_w[1], aw2 = attn_w[2];
    const float iws = fast_rcp(aw0 + aw1 + aw2);
    const f32x4* p = (const f32x4*)po;
    const int NQ = BB*SS;

    f32x4 s01 = p[(size_t)0*65536 + v] + p[(size_t)1*65536 + v];
    f32x4 s23 = p[(size_t)2*65536 + v] + p[(size_t)3*65536 + v];
    f32x4 s3s = {0,0,0,0};
    float l3 = 0.f;
    #pragma unroll
    for (int s = 0; s < 8; ++s) {
        if (s < ns) {
            s3s += p[(size_t)(4+s)*65536 + v];
            l3 += lb[(4+s)*NQ + qg];
        }
    }
    const float f0 = aw0 * iws * fast_rcp(lb[0*NQ + qg] + lb[1*NQ + qg]);
    const float f1 = aw1 * iws * fast_rcp(lb[2*NQ + qg] + lb[3*NQ + qg]);
    const float f2 = aw2 * iws * fast_rcp(l3);
    f32x4 o;
    #pragma unroll
    for (int u = 0; u < 4; ++u)
        o[u] = __builtin_fmaf(s01[u], f0,
               __builtin_fmaf(s23[u], f1, s3s[u]*f2));
    ((f32x4*)out)[v] = o;
}

extern "C" void kernel_launch(void* const* d_in, const int* in_sizes, int n_in,
                              void* d_out, int out_size, void* d_ws, size_t ws_size,
                              hipStream_t stream) {
    (void)in_sizes; (void)n_in; (void)out_size; (void)ws_size;
    const float* x          = (const float*)d_in[0];
    const float* Wq         = (const float*)d_in[1];
    const float* Wk         = (const float*)d_in[2];
    const float* bk         = (const float*)d_in[3];
    const float* Wv         = (const float*)d_in[4];
    const float* attn_w     = (const float*)d_in[5];
    const float* attn_scale = (const float*)d_in[6];
    float* out              = (float*)d_out;

    // workspace carve-up (~26 MB)
    float* exf = (float*)d_ws;                            // [B,S,64] f32
    unsigned short* qh  = (unsigned short*)(exf + NSD);   // 6 bf16 [B,S,64]
    unsigned short* ql  = qh  + NSD;
    unsigned short* kh  = ql  + NSD;
    unsigned short* kl  = kh  + NSD;
    unsigned short* xh  = kl  + NSD;
    unsigned short* xlo = xh  + NSD;
    unsigned short* xT  = xlo + NSD;                      // bf16 [B,64,S]
    unsigned short* vT  = xT  + NSD;
    float* po = (float*)(vT + NSD);                       // [12][B,S,64] f32
    float* lb = po + (size_t)12*NSD;                      // [12][B*S]

    k_proj <<<1024, 256, 0, stream>>>(x, Wq, Wk, bk, Wv,
                                      qh, ql, kh, kl, xh, xlo, exf, xT, vT);
    k_fused<<<1600, 256, 0, stream>>>(xh, xlo, qh, ql, kh, kl, exf, xT, vT,
                                      attn_scale, po, lb);
    k_comb <<<256, 256, 0, stream>>>(po, lb, attn_w, out);
}